// Round 1
// baseline (283.464 us; speedup 1.0000x reference)
//
#include <hip/hip_runtime.h>
#include <hip/hip_bf16.h>

typedef unsigned long long ull;

#define B_ROWS 32768
#define D_COLS 2048
#define K_SEL  40
#define T_LO   1.5f
#define CAP    256          // candidate capacity per row (count(x>1.5) ~ 137 +- 11)
#define ALPHA_F  0.01f
#define TARGET_F 0.01953125f   // 40/2048 exact

__device__ __forceinline__ ull fkey(float vv, unsigned col) {
    // monotone (value desc handled by max, index asc via ~col) 64-bit key
    unsigned bits = __float_as_uint(vv);
    unsigned sk = (bits & 0x80000000u) ? ~bits : (bits | 0x80000000u);
    return ((ull)sk << 32) | (ull)(unsigned)(~col);
}

// Kernel 1: per-row exact top-K. One wave per row. Writes 40 (val,col) pairs
// into the first 320B of the row's slice of `out` (used as scratch; kernel 3
// overwrites the whole row), and accumulates per-column selection counts.
__global__ __launch_bounds__(256) void kwta_topk_kernel(
        const float* __restrict__ x, float* __restrict__ out,
        unsigned* __restrict__ cnt) {
    __shared__ float2 cands[4][CAP];

    const int lane = threadIdx.x & 63;
    const int wid  = threadIdx.x >> 6;
    const int row  = blockIdx.x * 4 + wid;
    const float* xr = x + (size_t)row * D_COLS;
    const ull lm_lt = (1ull << lane) - 1ull;

    // ---- load 32 elements/lane, coalesced ----
    float4 v[8];
#pragma unroll
    for (int s = 0; s < 8; ++s)
        v[s] = *reinterpret_cast<const float4*>(xr + s * 256 + lane * 4);

    // ---- compact candidates (val > T_LO) into LDS via ballot prefix ----
    float2* my = cands[wid];
    unsigned base = 0;
    auto push = [&](float val, unsigned col) {
        bool p = val > T_LO;
        ull bal = __ballot(p);
        if (p) {
            unsigned pos = base + (unsigned)__popcll(bal & lm_lt);
            if (pos < CAP) my[pos] = make_float2(val, __uint_as_float(col));
        }
        base += (unsigned)__popcll(bal);
    };
#pragma unroll
    for (int s = 0; s < 8; ++s) {
        unsigned c0 = (unsigned)(s * 256 + lane * 4);
        push(v[s].x, c0); push(v[s].y, c0 + 1);
        push(v[s].z, c0 + 2); push(v[s].w, c0 + 3);
    }
    __syncthreads();   // uniform across block; LDS visible for read-back

    const unsigned C = base;
    float* hdr = out + (size_t)row * D_COLS;

    if (C >= K_SEL && C <= CAP) {
        // ---- primary path: bitwise radix-select over candidate float bits ----
        unsigned kbits[4], ccol[4];
        float    cval[4];
        ull alive[4];
#pragma unroll
        for (int j = 0; j < 4; ++j) {
            unsigned idx = (unsigned)(j * 64 + lane);
            float2 cd = my[idx];
            bool ok = idx < C;
            cval[j]  = ok ? cd.x : 0.0f;
            kbits[j] = __float_as_uint(cval[j]);       // >1.5 => positive => raw-bit order
            ccol[j]  = __float_as_uint(cd.y);
            unsigned lo = (unsigned)(j * 64);
            ull a;
            if (C >= lo + 64)      a = ~0ull;
            else if (C <= lo)      a = 0ull;
            else                   a = (1ull << (C - lo)) - 1ull;
            alive[j] = a;
        }

        unsigned p = 0, kk = K_SEL;
        for (int b = 30; b >= 0; --b) {
            unsigned bit = 1u << b;
            ull bm[4];
            unsigned cv = 0;
#pragma unroll
            for (int j = 0; j < 4; ++j) {
                bm[j] = __ballot((kbits[j] & bit) != 0) & alive[j];
                cv += (unsigned)__popcll(bm[j]);
            }
            bool take = (cv >= kk);
            if (take) p |= bit; else kk -= cv;
#pragma unroll
            for (int j = 0; j < 4; ++j)
                alive[j] = take ? bm[j] : (alive[j] & ~bm[j]);
        }
        // p = bits of K-th largest value; alive = candidates equal to it;
        // kk = how many equals belong in the top-K (smallest column first).
        ull sel[4];
        unsigned neq = 0;
#pragma unroll
        for (int j = 0; j < 4; ++j) {
            sel[j] = __ballot(kbits[j] > p);
            neq += (unsigned)__popcll(alive[j]);
        }
        if (neq == kk) {
#pragma unroll
            for (int j = 0; j < 4; ++j) sel[j] |= alive[j];
        } else {
            // ultra-rare exact tie at threshold: pick kk smallest columns
            ull eq[4] = {alive[0], alive[1], alive[2], alive[3]};
            for (unsigned t = 0; t < kk; ++t) {
                unsigned mymin = 0xFFFFFFFFu;
#pragma unroll
                for (int j = 0; j < 4; ++j)
                    if ((eq[j] >> lane) & 1ull) mymin = min(mymin, ccol[j]);
#pragma unroll
                for (int off = 32; off >= 1; off >>= 1)
                    mymin = min(mymin, (unsigned)__shfl_xor((int)mymin, off, 64));
#pragma unroll
                for (int j = 0; j < 4; ++j) {
                    bool hit = ((eq[j] >> lane) & 1ull) && (ccol[j] == mymin);
                    ull hb = __ballot(hit);
                    sel[j] |= hb; eq[j] &= ~hb;
                }
            }
        }
        // ---- emit the 40 selected (val,col) pairs + column counts ----
        unsigned pref = 0;
#pragma unroll
        for (int j = 0; j < 4; ++j) {
            if ((sel[j] >> lane) & 1ull) {
                unsigned pos = pref + (unsigned)__popcll(sel[j] & lm_lt);
                reinterpret_cast<float2*>(hdr)[pos] =
                    make_float2(cval[j], __uint_as_float(ccol[j]));
                atomicAdd(&cnt[ccol[j]], 1u);
            }
            pref += (unsigned)__popcll(sel[j]);
        }
    } else {
        // ---- fully general fallback (never triggers for N(0,1) data):
        //      K rounds of exact wave-argmax with (value desc, index asc) key
        unsigned rm = 0;  // removed bitmap over my 32 slots
        for (int t = 0; t < K_SEL; ++t) {
            ull best = 0;
#pragma unroll
            for (int s = 0; s < 8; ++s) {
                unsigned c0 = (unsigned)(s * 256 + lane * 4);
                float q[4] = {v[s].x, v[s].y, v[s].z, v[s].w};
#pragma unroll
                for (int j = 0; j < 4; ++j) {
                    int slot = s * 4 + j;
                    if (!((rm >> slot) & 1u)) {
                        ull key = fkey(q[j], c0 + j);
                        best = best > key ? best : key;
                    }
                }
            }
#pragma unroll
            for (int off = 32; off >= 1; off >>= 1) {
                ull o = __shfl_xor(best, off, 64);
                best = best > o ? best : o;
            }
#pragma unroll
            for (int s = 0; s < 8; ++s) {
                unsigned c0 = (unsigned)(s * 256 + lane * 4);
                float q[4] = {v[s].x, v[s].y, v[s].z, v[s].w};
#pragma unroll
                for (int j = 0; j < 4; ++j) {
                    int slot = s * 4 + j;
                    if (!((rm >> slot) & 1u) && fkey(q[j], c0 + j) == best) {
                        rm |= 1u << slot;
                        reinterpret_cast<float2*>(hdr)[t] =
                            make_float2(q[j], __uint_as_float(c0 + j));
                        atomicAdd(&cnt[c0 + j], 1u);
                    }
                }
            }
        }
    }
}

// Kernel 2: boost[d] = exp(-(duty*0.99 + 0.01*cnt/B - target))
__global__ void kwta_boost_kernel(const float* __restrict__ duty,
                                  const unsigned* __restrict__ cnt,
                                  float* __restrict__ boost) {
    int d = blockIdx.x * blockDim.x + threadIdx.x;
    if (d < D_COLS) {
        float mean = (float)cnt[d] * (1.0f / 32768.0f);
        float nd = duty[d] * (1.0f - ALPHA_F) + ALPHA_F * mean;
        boost[d] = expf(-(nd - TARGET_F));
    }
}

// Kernel 3: block-per-row. Read the 40 pairs from the row header, build the
// full row in LDS, write coalesced float4s (overwrites header with output).
__global__ __launch_bounds__(256) void kwta_scatter_kernel(
        float* __restrict__ out, const float* __restrict__ boost) {
    __shared__ float buf[D_COLS];
    const int t = threadIdx.x;
    const size_t rb = (size_t)blockIdx.x * D_COLS;

    float2 pr = make_float2(0.0f, 0.0f);
    if (t < K_SEL) pr = reinterpret_cast<const float2*>(out + rb)[t];

    float4 z = make_float4(0.0f, 0.0f, 0.0f, 0.0f);
    reinterpret_cast<float4*>(buf)[t * 2]     = z;
    reinterpret_cast<float4*>(buf)[t * 2 + 1] = z;
    __syncthreads();

    if (t < K_SEL) {
        unsigned col = __float_as_uint(pr.y);
        buf[col] = pr.x * boost[col];
    }
    __syncthreads();

    reinterpret_cast<float4*>(out + rb)[t * 2]     = reinterpret_cast<const float4*>(buf)[t * 2];
    reinterpret_cast<float4*>(out + rb)[t * 2 + 1] = reinterpret_cast<const float4*>(buf)[t * 2 + 1];
}

extern "C" void kernel_launch(void* const* d_in, const int* in_sizes, int n_in,
                              void* d_out, int out_size, void* d_ws, size_t ws_size,
                              hipStream_t stream) {
    const float* x    = (const float*)d_in[0];
    const float* duty = (const float*)d_in[1];
    float* out = (float*)d_out;

    unsigned* cnt  = (unsigned*)d_ws;                       // 2048 * 4B
    float*    boost = (float*)((char*)d_ws + 8192);         // 2048 * 4B

    hipMemsetAsync(d_ws, 0, D_COLS * sizeof(unsigned), stream);

    kwta_topk_kernel<<<B_ROWS / 4, 256, 0, stream>>>(x, out, cnt);
    kwta_boost_kernel<<<D_COLS / 256, 256, 0, stream>>>(duty, cnt, boost);
    kwta_scatter_kernel<<<B_ROWS, 256, 0, stream>>>(out, boost);
}

// Round 2
// 269.016 us; speedup vs baseline: 1.0537x; 1.0537x over previous
//
#include <hip/hip_runtime.h>
#include <hip/hip_bf16.h>

typedef unsigned long long ull;

#define B_ROWS 32768
#define D_COLS 2048
#define K_SEL  40
#define T_LO   1.74f          // P(x>1.74)=0.0409 -> C ~ 84 +- 9, in [40,128] at ~4.9 sigma
#define CAP    128            // 2 slots per lane
#define ALPHA_F  0.01f
#define TARGET_F 0.01953125f  // 40/2048 exact

__device__ __forceinline__ ull fkey(float vv, unsigned col) {
    // monotone (value desc via max, index asc via ~col) 64-bit key
    unsigned bits = __float_as_uint(vv);
    unsigned sk = (bits & 0x80000000u) ? ~bits : (bits | 0x80000000u);
    return ((ull)sk << 32) | (ull)(unsigned)(~col);
}

__device__ __forceinline__ float f4elem(const float4& q, int j) {
    return j == 0 ? q.x : j == 1 ? q.y : j == 2 ? q.z : q.w;
}

// Kernel 1: per-row exact top-K, one wave per row, no inter-wave sync.
// Emits 40 (val,col) pairs into the first 320B of the row's out-slice
// (scratch; kernel 3 overwrites the row) + per-column selection counts.
__global__ __launch_bounds__(256, 8) void kwta_topk_kernel(
        const float* __restrict__ x, float* __restrict__ out,
        unsigned* __restrict__ cnt) {
    __shared__ float2 cands[4][CAP];

    const int lane = threadIdx.x & 63;
    const int wid  = threadIdx.x >> 6;
    const int row  = blockIdx.x * 4 + wid;
    const float* xr = x + (size_t)row * D_COLS;
    const ull lm_lt = (1ull << lane) - 1ull;
    float2* my = cands[wid];
    float* hdr = out + (size_t)row * D_COLS;

    // ---- load 32 elements/lane, coalesced (8 independent dwordx4) ----
    float4 v[8];
#pragma unroll
    for (int s = 0; s < 8; ++s)
        v[s] = *reinterpret_cast<const float4*>(xr + s * 256 + lane * 4);

    // ---- per-lane candidate predicate mask (32 independent compares) ----
    unsigned m = 0;
#pragma unroll
    for (int s = 0; s < 8; ++s) {
#pragma unroll
        for (int j = 0; j < 4; ++j)
            m |= (f4elem(v[s], j) > T_LO ? 1u : 0u) << (s * 4 + j);
    }
    unsigned mycnt = __popc(m);

    // ---- wave-wide exclusive scan of per-lane counts (6 shfl steps) ----
    unsigned inc = mycnt;
#pragma unroll
    for (int d = 1; d < 64; d <<= 1) {
        unsigned u = __shfl_up(inc, d, 64);
        if (lane >= d) inc += u;
    }
    const unsigned base = inc - mycnt;
    const unsigned C = __shfl(inc, 63, 64);   // total candidates this row

    // ---- predicated LDS compaction (order irrelevant; cols carried) ----
    {
        unsigned pos = base;
#pragma unroll
        for (int s = 0; s < 8; ++s) {
#pragma unroll
            for (int j = 0; j < 4; ++j) {
                if (((m >> (s * 4 + j)) & 1u) && pos < CAP) {
                    my[pos] = make_float2(f4elem(v[s], j),
                                          __uint_as_float((unsigned)(s * 256 + lane * 4 + j)));
                    ++pos;
                }
            }
        }
    }

    if (C >= K_SEL && C <= CAP) {
        // ---- primary: early-exit bitwise radix select over 2 slots/lane ----
        float2 cd0 = my[lane];
        float2 cd1 = my[64 + lane];
        const bool ok0 = (unsigned)lane < C;
        const bool ok1 = (unsigned)(64 + lane) < C;
        const float    cv0 = ok0 ? cd0.x : 0.0f;
        const float    cv1 = ok1 ? cd1.x : 0.0f;
        const unsigned kb0 = __float_as_uint(cv0);  // >1.74 => positive => raw-bit order
        const unsigned kb1 = __float_as_uint(cv1);
        const unsigned cc0 = __float_as_uint(cd0.y);
        const unsigned cc1 = __float_as_uint(cd1.y);

        ull a0 = (C >= 64) ? ~0ull : ((1ull << C) - 1ull);
        ull a1 = (C <= 64) ? 0ull : ((C >= 128) ? ~0ull : ((1ull << (C - 64)) - 1ull));
        ull s0 = 0, s1 = 0;
        unsigned kk = K_SEL, na = C;

        if (na == kk) { s0 = a0; s1 = a1; kk = 0; }
        for (int b = 30; b >= 0 && kk; --b) {
            unsigned bit = 1u << b;
            ull b0 = __ballot((kb0 & bit) != 0) & a0;
            ull b1 = __ballot((kb1 & bit) != 0) & a1;
            unsigned cv = (unsigned)__popcll(b0) + (unsigned)__popcll(b1);
            if (cv >= kk) { a0 = b0; a1 = b1; na = cv; }
            else          { s0 |= b0; s1 |= b1; kk -= cv; a0 &= ~b0; a1 &= ~b1; na -= cv; }
            if (na == kk) { s0 |= a0; s1 |= a1; kk = 0; }
        }
        if (kk) {
            // bits exhausted: alive are exactly-equal values; take kk smallest cols
            ull e0 = a0, e1 = a1;
            for (unsigned t = 0; t < kk; ++t) {
                unsigned mymin = 0xFFFFFFFFu;
                if ((e0 >> lane) & 1ull) mymin = min(mymin, cc0);
                if ((e1 >> lane) & 1ull) mymin = min(mymin, cc1);
#pragma unroll
                for (int off = 32; off >= 1; off >>= 1)
                    mymin = min(mymin, (unsigned)__shfl_xor((int)mymin, off, 64));
                bool h0 = ((e0 >> lane) & 1ull) && cc0 == mymin;
                bool h1 = ((e1 >> lane) & 1ull) && cc1 == mymin;
                ull hb0 = __ballot(h0) & e0;
                ull hb1 = __ballot(h1) & e1;
                if (hb0) { s0 |= hb0 & (~hb0 + 1); e0 &= ~(hb0 & (~hb0 + 1)); }
                else     { s1 |= hb1 & (~hb1 + 1); e1 &= ~(hb1 & (~hb1 + 1)); }
            }
        }

        // ---- emit 40 pairs + column counts ----
        unsigned n0 = (unsigned)__popcll(s0);
        if ((s0 >> lane) & 1ull) {
            unsigned pos = (unsigned)__popcll(s0 & lm_lt);
            reinterpret_cast<float2*>(hdr)[pos] = make_float2(cv0, __uint_as_float(cc0));
            atomicAdd(&cnt[cc0], 1u);
        }
        if ((s1 >> lane) & 1ull) {
            unsigned pos = n0 + (unsigned)__popcll(s1 & lm_lt);
            reinterpret_cast<float2*>(hdr)[pos] = make_float2(cv1, __uint_as_float(cc1));
            atomicAdd(&cnt[cc1], 1u);
        }
    } else {
        // ---- fully general fallback (statistically never for N(0,1) data):
        //      K exact wave-argmax rounds, reloading from global (L1/L2-hot)
        unsigned rm = 0;
        for (int t = 0; t < K_SEL; ++t) {
            ull best = 0;
#pragma unroll
            for (int s = 0; s < 8; ++s) {
                float4 q = *reinterpret_cast<const float4*>(xr + s * 256 + lane * 4);
#pragma unroll
                for (int j = 0; j < 4; ++j) {
                    int slot = s * 4 + j;
                    if (!((rm >> slot) & 1u)) {
                        ull key = fkey(f4elem(q, j), (unsigned)(s * 256 + lane * 4 + j));
                        best = best > key ? best : key;
                    }
                }
            }
#pragma unroll
            for (int off = 32; off >= 1; off >>= 1) {
                ull o = __shfl_xor(best, off, 64);
                best = best > o ? best : o;
            }
#pragma unroll
            for (int s = 0; s < 8; ++s) {
                float4 q = *reinterpret_cast<const float4*>(xr + s * 256 + lane * 4);
#pragma unroll
                for (int j = 0; j < 4; ++j) {
                    int slot = s * 4 + j;
                    unsigned col = (unsigned)(s * 256 + lane * 4 + j);
                    if (!((rm >> slot) & 1u) && fkey(f4elem(q, j), col) == best) {
                        rm |= 1u << slot;
                        reinterpret_cast<float2*>(hdr)[t] =
                            make_float2(f4elem(q, j), __uint_as_float(col));
                        atomicAdd(&cnt[col], 1u);
                    }
                }
            }
        }
    }
}

// Kernel 2: boost[d] = exp(-(duty*0.99 + 0.01*cnt/B - target))
__global__ void kwta_boost_kernel(const float* __restrict__ duty,
                                  const unsigned* __restrict__ cnt,
                                  float* __restrict__ boost) {
    int d = blockIdx.x * blockDim.x + threadIdx.x;
    if (d < D_COLS) {
        float mean = (float)cnt[d] * (1.0f / 32768.0f);
        float nd = duty[d] * (1.0f - ALPHA_F) + ALPHA_F * mean;
        boost[d] = expf(-(nd - TARGET_F));
    }
}

// Kernel 3: block-per-row; read 40 pairs from row header, build row in LDS,
// write fully-coalesced float4s (overwrites header with the real output).
__global__ __launch_bounds__(256) void kwta_scatter_kernel(
        float* __restrict__ out, const float* __restrict__ boost) {
    __shared__ float buf[D_COLS];
    const int t = threadIdx.x;
    const size_t rb = (size_t)blockIdx.x * D_COLS;

    float2 pr = make_float2(0.0f, 0.0f);
    if (t < K_SEL) pr = reinterpret_cast<const float2*>(out + rb)[t];

    float4 z = make_float4(0.0f, 0.0f, 0.0f, 0.0f);
    reinterpret_cast<float4*>(buf)[t * 2]     = z;
    reinterpret_cast<float4*>(buf)[t * 2 + 1] = z;
    __syncthreads();

    if (t < K_SEL) {
        unsigned col = __float_as_uint(pr.y);
        buf[col] = pr.x * boost[col];
    }
    __syncthreads();

    reinterpret_cast<float4*>(out + rb)[t * 2]     = reinterpret_cast<const float4*>(buf)[t * 2];
    reinterpret_cast<float4*>(out + rb)[t * 2 + 1] = reinterpret_cast<const float4*>(buf)[t * 2 + 1];
}

extern "C" void kernel_launch(void* const* d_in, const int* in_sizes, int n_in,
                              void* d_out, int out_size, void* d_ws, size_t ws_size,
                              hipStream_t stream) {
    const float* x    = (const float*)d_in[0];
    const float* duty = (const float*)d_in[1];
    float* out = (float*)d_out;

    unsigned* cnt   = (unsigned*)d_ws;               // 2048 * 4B
    float*    boost = (float*)((char*)d_ws + 8192);  // 2048 * 4B

    hipMemsetAsync(d_ws, 0, D_COLS * sizeof(unsigned), stream);

    kwta_topk_kernel<<<B_ROWS / 4, 256, 0, stream>>>(x, out, cnt);
    kwta_boost_kernel<<<D_COLS / 256, 256, 0, stream>>>(duty, cnt, boost);
    kwta_scatter_kernel<<<B_ROWS, 256, 0, stream>>>(out, boost);
}

// Round 3
// 193.670 us; speedup vs baseline: 1.4636x; 1.3890x over previous
//
#include <hip/hip_runtime.h>
#include <hip/hip_bf16.h>

typedef unsigned long long ull;

#define B_ROWS 32768
#define D_COLS 2048
#define K_SEL  40
#define T_LO   1.74f          // P(x>1.74)=0.0409 -> C ~ 84 +- 9, in [40,128] at ~4.9 sigma
#define CAP    128            // 2 slots per lane
#define ALPHA_F  0.01f
#define TARGET_F 0.01953125f  // 40/2048 exact

__device__ __forceinline__ ull fkey(float vv, unsigned col) {
    // monotone (value desc via max, index asc via ~col) 64-bit key
    unsigned bits = __float_as_uint(vv);
    unsigned sk = (bits & 0x80000000u) ? ~bits : (bits | 0x80000000u);
    return ((ull)sk << 32) | (ull)(unsigned)(~col);
}

__device__ __forceinline__ float f4elem(const float4& q, int j) {
    return j == 0 ? q.x : j == 1 ? q.y : j == 2 ? q.z : q.w;
}

// Kernel 1: per-row exact top-K, one wave per row. Emits 40 (val,col) pairs
// into the first 320B of the row's out-slice (scratch; kernel 3 overwrites
// the row) + per-column selection counts into a PRIVATIZED histogram copy
// (copy = blockIdx & (G-1); G multiple of 8 => each copy is XCD-local).
__global__ __launch_bounds__(256, 8) void kwta_topk_kernel(
        const float* __restrict__ x, float* __restrict__ out,
        unsigned* __restrict__ cnt, int gmask) {
    __shared__ float2 cands[4][CAP];

    const int lane = threadIdx.x & 63;
    const int wid  = threadIdx.x >> 6;
    const int row  = blockIdx.x * 4 + wid;
    const float* xr = x + (size_t)row * D_COLS;
    const ull lm_lt = (1ull << lane) - 1ull;
    float2* my = cands[wid];
    float* hdr = out + (size_t)row * D_COLS;
    unsigned* mycnt_arr = cnt + ((size_t)(blockIdx.x & gmask) << 11);

    // ---- load 32 elements/lane, coalesced (8 independent dwordx4) ----
    float4 v[8];
#pragma unroll
    for (int s = 0; s < 8; ++s)
        v[s] = *reinterpret_cast<const float4*>(xr + s * 256 + lane * 4);

    // ---- per-lane candidate predicate mask (32 independent compares) ----
    unsigned m = 0;
#pragma unroll
    for (int s = 0; s < 8; ++s) {
#pragma unroll
        for (int j = 0; j < 4; ++j)
            m |= (f4elem(v[s], j) > T_LO ? 1u : 0u) << (s * 4 + j);
    }
    unsigned mycnt = __popc(m);

    // ---- wave-wide exclusive scan of per-lane counts (6 shfl steps) ----
    unsigned inc = mycnt;
#pragma unroll
    for (int d = 1; d < 64; d <<= 1) {
        unsigned u = __shfl_up(inc, d, 64);
        if (lane >= d) inc += u;
    }
    const unsigned base = inc - mycnt;
    const unsigned C = __shfl(inc, 63, 64);   // total candidates this row

    // ---- predicated LDS compaction (order irrelevant; cols carried) ----
    {
        unsigned pos = base;
#pragma unroll
        for (int s = 0; s < 8; ++s) {
#pragma unroll
            for (int j = 0; j < 4; ++j) {
                if (((m >> (s * 4 + j)) & 1u) && pos < CAP) {
                    my[pos] = make_float2(f4elem(v[s], j),
                                          __uint_as_float((unsigned)(s * 256 + lane * 4 + j)));
                    ++pos;
                }
            }
        }
    }

    if (C >= K_SEL && C <= CAP) {
        // ---- primary: early-exit bitwise radix select over 2 slots/lane ----
        float2 cd0 = my[lane];
        float2 cd1 = my[64 + lane];
        const bool ok0 = (unsigned)lane < C;
        const bool ok1 = (unsigned)(64 + lane) < C;
        const float    cv0 = ok0 ? cd0.x : 0.0f;
        const float    cv1 = ok1 ? cd1.x : 0.0f;
        const unsigned kb0 = __float_as_uint(cv0);  // >1.74 => positive => raw-bit order
        const unsigned kb1 = __float_as_uint(cv1);
        const unsigned cc0 = __float_as_uint(cd0.y);
        const unsigned cc1 = __float_as_uint(cd1.y);

        ull a0 = (C >= 64) ? ~0ull : ((1ull << C) - 1ull);
        ull a1 = (C <= 64) ? 0ull : ((C >= 128) ? ~0ull : ((1ull << (C - 64)) - 1ull));
        ull s0 = 0, s1 = 0;
        unsigned kk = K_SEL, na = C;

        if (na == kk) { s0 = a0; s1 = a1; kk = 0; }
        for (int b = 30; b >= 0 && kk; --b) {
            unsigned bit = 1u << b;
            ull b0 = __ballot((kb0 & bit) != 0) & a0;
            ull b1 = __ballot((kb1 & bit) != 0) & a1;
            unsigned cv = (unsigned)__popcll(b0) + (unsigned)__popcll(b1);
            if (cv >= kk) { a0 = b0; a1 = b1; na = cv; }
            else          { s0 |= b0; s1 |= b1; kk -= cv; a0 &= ~b0; a1 &= ~b1; na -= cv; }
            if (na == kk) { s0 |= a0; s1 |= a1; kk = 0; }
        }
        if (kk) {
            // bits exhausted: alive are exactly-equal values; take kk smallest cols
            ull e0 = a0, e1 = a1;
            for (unsigned t = 0; t < kk; ++t) {
                unsigned mymin = 0xFFFFFFFFu;
                if ((e0 >> lane) & 1ull) mymin = min(mymin, cc0);
                if ((e1 >> lane) & 1ull) mymin = min(mymin, cc1);
#pragma unroll
                for (int off = 32; off >= 1; off >>= 1)
                    mymin = min(mymin, (unsigned)__shfl_xor((int)mymin, off, 64));
                bool h0 = ((e0 >> lane) & 1ull) && cc0 == mymin;
                bool h1 = ((e1 >> lane) & 1ull) && cc1 == mymin;
                ull hb0 = __ballot(h0) & e0;
                ull hb1 = __ballot(h1) & e1;
                if (hb0) { s0 |= hb0 & (~hb0 + 1); e0 &= ~(hb0 & (~hb0 + 1)); }
                else     { s1 |= hb1 & (~hb1 + 1); e1 &= ~(hb1 & (~hb1 + 1)); }
            }
        }

        // ---- emit 40 pairs + column counts (XCD-local histogram copy) ----
        unsigned n0 = (unsigned)__popcll(s0);
        if ((s0 >> lane) & 1ull) {
            unsigned pos = (unsigned)__popcll(s0 & lm_lt);
            reinterpret_cast<float2*>(hdr)[pos] = make_float2(cv0, __uint_as_float(cc0));
            atomicAdd(&mycnt_arr[cc0], 1u);
        }
        if ((s1 >> lane) & 1ull) {
            unsigned pos = n0 + (unsigned)__popcll(s1 & lm_lt);
            reinterpret_cast<float2*>(hdr)[pos] = make_float2(cv1, __uint_as_float(cc1));
            atomicAdd(&mycnt_arr[cc1], 1u);
        }
    } else {
        // ---- fully general fallback (statistically never for N(0,1) data):
        //      K exact wave-argmax rounds, reloading from global (L1/L2-hot)
        unsigned rm = 0;
        for (int t = 0; t < K_SEL; ++t) {
            ull best = 0;
#pragma unroll
            for (int s = 0; s < 8; ++s) {
                float4 q = *reinterpret_cast<const float4*>(xr + s * 256 + lane * 4);
#pragma unroll
                for (int j = 0; j < 4; ++j) {
                    int slot = s * 4 + j;
                    if (!((rm >> slot) & 1u)) {
                        ull key = fkey(f4elem(q, j), (unsigned)(s * 256 + lane * 4 + j));
                        best = best > key ? best : key;
                    }
                }
            }
#pragma unroll
            for (int off = 32; off >= 1; off >>= 1) {
                ull o = __shfl_xor(best, off, 64);
                best = best > o ? best : o;
            }
#pragma unroll
            for (int s = 0; s < 8; ++s) {
                float4 q = *reinterpret_cast<const float4*>(xr + s * 256 + lane * 4);
#pragma unroll
                for (int j = 0; j < 4; ++j) {
                    int slot = s * 4 + j;
                    unsigned col = (unsigned)(s * 256 + lane * 4 + j);
                    if (!((rm >> slot) & 1u) && fkey(f4elem(q, j), col) == best) {
                        rm |= 1u << slot;
                        reinterpret_cast<float2*>(hdr)[t] =
                            make_float2(f4elem(q, j), __uint_as_float(col));
                        atomicAdd(&mycnt_arr[col], 1u);
                    }
                }
            }
        }
    }
}

// Kernel 2: sum G histogram copies; boost[d] = exp(-(duty*0.99 + 0.01*cnt/B - target))
__global__ void kwta_boost_kernel(const float* __restrict__ duty,
                                  const unsigned* __restrict__ cnt,
                                  float* __restrict__ boost, int G) {
    int d = blockIdx.x * blockDim.x + threadIdx.x;
    if (d < D_COLS) {
        unsigned s = 0;
        for (int g = 0; g < G; ++g) s += cnt[((size_t)g << 11) + d];
        float mean = (float)s * (1.0f / 32768.0f);
        float nd = duty[d] * (1.0f - ALPHA_F) + ALPHA_F * mean;
        boost[d] = expf(-(nd - TARGET_F));
    }
}

// Kernel 3: block-per-row; read 40 pairs from row header, build row in LDS,
// write fully-coalesced float4s (overwrites header with the real output).
__global__ __launch_bounds__(256) void kwta_scatter_kernel(
        float* __restrict__ out, const float* __restrict__ boost) {
    __shared__ float buf[D_COLS];
    const int t = threadIdx.x;
    const size_t rb = (size_t)blockIdx.x * D_COLS;

    float2 pr = make_float2(0.0f, 0.0f);
    if (t < K_SEL) pr = reinterpret_cast<const float2*>(out + rb)[t];

    float4 z = make_float4(0.0f, 0.0f, 0.0f, 0.0f);
    reinterpret_cast<float4*>(buf)[t * 2]     = z;
    reinterpret_cast<float4*>(buf)[t * 2 + 1] = z;
    __syncthreads();

    if (t < K_SEL) {
        unsigned col = __float_as_uint(pr.y);
        buf[col] = pr.x * boost[col];
    }
    __syncthreads();

    reinterpret_cast<float4*>(out + rb)[t * 2]     = reinterpret_cast<const float4*>(buf)[t * 2];
    reinterpret_cast<float4*>(out + rb)[t * 2 + 1] = reinterpret_cast<const float4*>(buf)[t * 2 + 1];
}

extern "C" void kernel_launch(void* const* d_in, const int* in_sizes, int n_in,
                              void* d_out, int out_size, void* d_ws, size_t ws_size,
                              hipStream_t stream) {
    const float* x    = (const float*)d_in[0];
    const float* duty = (const float*)d_in[1];
    float* out = (float*)d_out;

    // Privatized histogram: G copies of 2048 u32 (8 KB each), G multiple of 8
    // => each copy touched by exactly one XCD (blocks round-robin over XCDs).
    // Deterministic: G depends only on ws_size (constant for the harness run).
    int G = 128;
    while (G > 1 && (size_t)G * 8192 + 8192 > ws_size) G >>= 1;

    unsigned* cnt   = (unsigned*)d_ws;                          // G * 8 KB
    float*    boost = (float*)((char*)d_ws + (size_t)G * 8192); // 8 KB

    hipMemsetAsync(d_ws, 0, (size_t)G * 8192, stream);

    kwta_topk_kernel<<<B_ROWS / 4, 256, 0, stream>>>(x, out, cnt, G - 1);
    kwta_boost_kernel<<<D_COLS / 256, 256, 0, stream>>>(duty, cnt, boost, G);
    kwta_scatter_kernel<<<B_ROWS, 256, 0, stream>>>(out, boost);
}

// Round 4
// 177.524 us; speedup vs baseline: 1.5968x; 1.0910x over previous
//
#include <hip/hip_runtime.h>
#include <hip/hip_bf16.h>

typedef unsigned long long ull;

#define B_ROWS 32768
#define D_COLS 2048
#define K_SEL  40
#define T_LO   1.74f          // P(x>1.74)=0.0409 -> C ~ 84 +- 9, in [40,128] at ~4.9 sigma
#define CAP    128            // 2 slots per lane
#define ALPHA_F  0.01f
#define TARGET_F 0.01953125f  // 40/2048 exact
#define G_COPIES 128          // histogram copies; multiple of 8 => XCD-local

__device__ __forceinline__ ull fkey(float vv, unsigned col) {
    // monotone (value desc via max, index asc via ~col) 64-bit key
    unsigned bits = __float_as_uint(vv);
    unsigned sk = (bits & 0x80000000u) ? ~bits : (bits | 0x80000000u);
    return ((ull)sk << 32) | (ull)(unsigned)(~col);
}

__device__ __forceinline__ float f4elem(const float4& q, int j) {
    return j == 0 ? q.x : j == 1 ? q.y : j == 2 ? q.z : q.w;
}

// Kernel 0: zero the privatized histograms (rocclr fillBuffer is 6.8 GB/s for
// small buffers -- 155us for 1MB! -- so do it ourselves at full BW).
__global__ __launch_bounds__(256) void kwta_zero_kernel(uint4* __restrict__ p) {
    p[blockIdx.x * 256 + threadIdx.x] = make_uint4(0u, 0u, 0u, 0u);
}

// Kernel 1: per-row exact top-K, one wave per row. Emits 40 (val,col) pairs
// into the first 320B of the row's out-slice (scratch; kernel 3 overwrites
// the row) + per-column selection counts into a PRIVATIZED histogram copy
// (copy = blockIdx & (G-1); G multiple of 8 => each copy is XCD-local).
__global__ __launch_bounds__(256, 8) void kwta_topk_kernel(
        const float* __restrict__ x, float* __restrict__ out,
        unsigned* __restrict__ cnt) {
    __shared__ float2 cands[4][CAP];

    const int lane = threadIdx.x & 63;
    const int wid  = threadIdx.x >> 6;
    const int row  = blockIdx.x * 4 + wid;
    const float* xr = x + (size_t)row * D_COLS;
    const ull lm_lt = (1ull << lane) - 1ull;
    float2* my = cands[wid];
    float* hdr = out + (size_t)row * D_COLS;
    unsigned* mycnt_arr = cnt + ((size_t)(blockIdx.x & (G_COPIES - 1)) << 11);

    // ---- load 32 elements/lane, coalesced (8 independent dwordx4) ----
    float4 v[8];
#pragma unroll
    for (int s = 0; s < 8; ++s)
        v[s] = *reinterpret_cast<const float4*>(xr + s * 256 + lane * 4);

    // ---- per-lane candidate predicate mask (32 independent compares) ----
    unsigned m = 0;
#pragma unroll
    for (int s = 0; s < 8; ++s) {
#pragma unroll
        for (int j = 0; j < 4; ++j)
            m |= (f4elem(v[s], j) > T_LO ? 1u : 0u) << (s * 4 + j);
    }
    unsigned mycnt = __popc(m);

    // ---- wave-wide exclusive scan of per-lane counts (6 shfl steps) ----
    unsigned inc = mycnt;
#pragma unroll
    for (int d = 1; d < 64; d <<= 1) {
        unsigned u = __shfl_up(inc, d, 64);
        if (lane >= d) inc += u;
    }
    const unsigned base = inc - mycnt;
    const unsigned C = __shfl(inc, 63, 64);   // total candidates this row

    // ---- predicated LDS compaction (order irrelevant; cols carried) ----
    {
        unsigned pos = base;
#pragma unroll
        for (int s = 0; s < 8; ++s) {
#pragma unroll
            for (int j = 0; j < 4; ++j) {
                if (((m >> (s * 4 + j)) & 1u) && pos < CAP) {
                    my[pos] = make_float2(f4elem(v[s], j),
                                          __uint_as_float((unsigned)(s * 256 + lane * 4 + j)));
                    ++pos;
                }
            }
        }
    }

    if (C >= K_SEL && C <= CAP) {
        // ---- primary: early-exit bitwise radix select over 2 slots/lane ----
        float2 cd0 = my[lane];
        float2 cd1 = my[64 + lane];
        const bool ok0 = (unsigned)lane < C;
        const bool ok1 = (unsigned)(64 + lane) < C;
        const float    cv0 = ok0 ? cd0.x : 0.0f;
        const float    cv1 = ok1 ? cd1.x : 0.0f;
        const unsigned kb0 = __float_as_uint(cv0);  // >1.74 => positive => raw-bit order
        const unsigned kb1 = __float_as_uint(cv1);
        const unsigned cc0 = __float_as_uint(cd0.y);
        const unsigned cc1 = __float_as_uint(cd1.y);

        ull a0 = (C >= 64) ? ~0ull : ((1ull << C) - 1ull);
        ull a1 = (C <= 64) ? 0ull : ((C >= 128) ? ~0ull : ((1ull << (C - 64)) - 1ull));
        ull s0 = 0, s1 = 0;
        unsigned kk = K_SEL, na = C;

        if (na == kk) { s0 = a0; s1 = a1; kk = 0; }
        for (int b = 30; b >= 0 && kk; --b) {
            unsigned bit = 1u << b;
            ull b0 = __ballot((kb0 & bit) != 0) & a0;
            ull b1 = __ballot((kb1 & bit) != 0) & a1;
            unsigned cv = (unsigned)__popcll(b0) + (unsigned)__popcll(b1);
            if (cv >= kk) { a0 = b0; a1 = b1; na = cv; }
            else          { s0 |= b0; s1 |= b1; kk -= cv; a0 &= ~b0; a1 &= ~b1; na -= cv; }
            if (na == kk) { s0 |= a0; s1 |= a1; kk = 0; }
        }
        if (kk) {
            // bits exhausted: alive are exactly-equal values; take kk smallest cols
            ull e0 = a0, e1 = a1;
            for (unsigned t = 0; t < kk; ++t) {
                unsigned mymin = 0xFFFFFFFFu;
                if ((e0 >> lane) & 1ull) mymin = min(mymin, cc0);
                if ((e1 >> lane) & 1ull) mymin = min(mymin, cc1);
#pragma unroll
                for (int off = 32; off >= 1; off >>= 1)
                    mymin = min(mymin, (unsigned)__shfl_xor((int)mymin, off, 64));
                bool h0 = ((e0 >> lane) & 1ull) && cc0 == mymin;
                bool h1 = ((e1 >> lane) & 1ull) && cc1 == mymin;
                ull hb0 = __ballot(h0) & e0;
                ull hb1 = __ballot(h1) & e1;
                if (hb0) { s0 |= hb0 & (~hb0 + 1); e0 &= ~(hb0 & (~hb0 + 1)); }
                else     { s1 |= hb1 & (~hb1 + 1); e1 &= ~(hb1 & (~hb1 + 1)); }
            }
        }

        // ---- emit 40 pairs + column counts (XCD-local histogram copy) ----
        unsigned n0 = (unsigned)__popcll(s0);
        if ((s0 >> lane) & 1ull) {
            unsigned pos = (unsigned)__popcll(s0 & lm_lt);
            reinterpret_cast<float2*>(hdr)[pos] = make_float2(cv0, __uint_as_float(cc0));
            atomicAdd(&mycnt_arr[cc0], 1u);
        }
        if ((s1 >> lane) & 1ull) {
            unsigned pos = n0 + (unsigned)__popcll(s1 & lm_lt);
            reinterpret_cast<float2*>(hdr)[pos] = make_float2(cv1, __uint_as_float(cc1));
            atomicAdd(&mycnt_arr[cc1], 1u);
        }
    } else {
        // ---- fully general fallback (statistically never for N(0,1) data):
        //      K exact wave-argmax rounds, reloading from global (L1/L2-hot)
        unsigned rm = 0;
        for (int t = 0; t < K_SEL; ++t) {
            ull best = 0;
#pragma unroll
            for (int s = 0; s < 8; ++s) {
                float4 q = *reinterpret_cast<const float4*>(xr + s * 256 + lane * 4);
#pragma unroll
                for (int j = 0; j < 4; ++j) {
                    int slot = s * 4 + j;
                    if (!((rm >> slot) & 1u)) {
                        ull key = fkey(f4elem(q, j), (unsigned)(s * 256 + lane * 4 + j));
                        best = best > key ? best : key;
                    }
                }
            }
#pragma unroll
            for (int off = 32; off >= 1; off >>= 1) {
                ull o = __shfl_xor(best, off, 64);
                best = best > o ? best : o;
            }
#pragma unroll
            for (int s = 0; s < 8; ++s) {
                float4 q = *reinterpret_cast<const float4*>(xr + s * 256 + lane * 4);
#pragma unroll
                for (int j = 0; j < 4; ++j) {
                    int slot = s * 4 + j;
                    unsigned col = (unsigned)(s * 256 + lane * 4 + j);
                    if (!((rm >> slot) & 1u) && fkey(f4elem(q, j), col) == best) {
                        rm |= 1u << slot;
                        reinterpret_cast<float2*>(hdr)[t] =
                            make_float2(f4elem(q, j), __uint_as_float(col));
                        atomicAdd(&mycnt_arr[col], 1u);
                    }
                }
            }
        }
    }
}

// Kernel 2: sum G histogram copies; boost[d] = exp(-(duty*0.99 + 0.01*cnt/B - target))
__global__ void kwta_boost_kernel(const float* __restrict__ duty,
                                  const unsigned* __restrict__ cnt,
                                  float* __restrict__ boost) {
    int d = blockIdx.x * blockDim.x + threadIdx.x;
    if (d < D_COLS) {
        unsigned s = 0;
        for (int g = 0; g < G_COPIES; ++g) s += cnt[((size_t)g << 11) + d];
        float mean = (float)s * (1.0f / 32768.0f);
        float nd = duty[d] * (1.0f - ALPHA_F) + ALPHA_F * mean;
        boost[d] = expf(-(nd - TARGET_F));
    }
}

// Kernel 3: block-per-row; read 40 pairs from row header, build row in LDS,
// write fully-coalesced float4s (overwrites header with the real output).
__global__ __launch_bounds__(256) void kwta_scatter_kernel(
        float* __restrict__ out, const float* __restrict__ boost) {
    __shared__ float buf[D_COLS];
    const int t = threadIdx.x;
    const size_t rb = (size_t)blockIdx.x * D_COLS;

    float2 pr = make_float2(0.0f, 0.0f);
    if (t < K_SEL) pr = reinterpret_cast<const float2*>(out + rb)[t];

    float4 z = make_float4(0.0f, 0.0f, 0.0f, 0.0f);
    reinterpret_cast<float4*>(buf)[t * 2]     = z;
    reinterpret_cast<float4*>(buf)[t * 2 + 1] = z;
    __syncthreads();

    if (t < K_SEL) {
        unsigned col = __float_as_uint(pr.y);
        buf[col] = pr.x * boost[col];
    }
    __syncthreads();

    reinterpret_cast<float4*>(out + rb)[t * 2]     = reinterpret_cast<const float4*>(buf)[t * 2];
    reinterpret_cast<float4*>(out + rb)[t * 2 + 1] = reinterpret_cast<const float4*>(buf)[t * 2 + 1];
}

extern "C" void kernel_launch(void* const* d_in, const int* in_sizes, int n_in,
                              void* d_out, int out_size, void* d_ws, size_t ws_size,
                              hipStream_t stream) {
    const float* x    = (const float*)d_in[0];
    const float* duty = (const float*)d_in[1];
    float* out = (float*)d_out;

    unsigned* cnt   = (unsigned*)d_ws;                               // G * 8 KB
    float*    boost = (float*)((char*)d_ws + (size_t)G_COPIES * 8192); // 8 KB

    // zero G*8KB = 1MB of histograms: 256 blocks x 256 threads x 16B
    kwta_zero_kernel<<<G_COPIES * 8192 / 4096, 256, 0, stream>>>((uint4*)d_ws);

    kwta_topk_kernel<<<B_ROWS / 4, 256, 0, stream>>>(x, out, cnt);
    kwta_boost_kernel<<<D_COLS / 256, 256, 0, stream>>>(duty, cnt, boost);
    kwta_scatter_kernel<<<B_ROWS, 256, 0, stream>>>(out, boost);
}

// Round 5
// 176.598 us; speedup vs baseline: 1.6051x; 1.0052x over previous
//
#include <hip/hip_runtime.h>
#include <hip/hip_bf16.h>

typedef unsigned long long ull;

#define B_ROWS 32768
#define D_COLS 2048
#define K_SEL  40
#define T_LO   1.74f          // P(x>1.74)=0.0409 -> C ~ 84 +- 9, in [40,128] at ~4.9 sigma
#define CAP    128            // 2 slots per lane
#define ALPHA_F  0.01f
#define TARGET_F 0.01953125f  // 40/2048 exact
#define G_COPIES 16           // histogram copies; multiple of 8 => XCD-local atomics

__device__ __forceinline__ ull fkey(float vv, unsigned col) {
    // monotone (value desc via max, index asc via ~col) 64-bit key
    unsigned bits = __float_as_uint(vv);
    unsigned sk = (bits & 0x80000000u) ? ~bits : (bits | 0x80000000u);
    return ((ull)sk << 32) | (ull)(unsigned)(~col);
}

__device__ __forceinline__ float f4elem(const float4& q, int j) {
    return j == 0 ? q.x : j == 1 ? q.y : j == 2 ? q.z : q.w;
}

// Kernel 0: zero the privatized histograms (rocclr fillBuffer launches a tiny
// grid for small buffers; ~18us serialized for 1MB. DIY at full BW.)
__global__ __launch_bounds__(256) void kwta_zero_kernel(uint4* __restrict__ p) {
    p[blockIdx.x * 256 + threadIdx.x] = make_uint4(0u, 0u, 0u, 0u);
}

// Kernel 1: per-row exact top-K, one wave per row. Emits 40 (val,col) pairs
// into the first 320B of the row's out-slice (scratch; kernel 3 overwrites
// the row) + per-column selection counts into a PRIVATIZED histogram copy
// (copy = blockIdx & 15; multiple of 8 => each copy stays XCD-local under
// round-robin block->XCD dispatch).
__global__ __launch_bounds__(256, 8) void kwta_topk_kernel(
        const float* __restrict__ x, float* __restrict__ out,
        unsigned* __restrict__ cnt) {
    __shared__ float2 cands[4][CAP];

    const int lane = threadIdx.x & 63;
    const int wid  = threadIdx.x >> 6;
    const int row  = blockIdx.x * 4 + wid;
    const float* xr = x + (size_t)row * D_COLS;
    const ull lm_lt = (1ull << lane) - 1ull;
    float2* my = cands[wid];
    float* hdr = out + (size_t)row * D_COLS;
    unsigned* mycnt_arr = cnt + ((size_t)(blockIdx.x & (G_COPIES - 1)) << 11);

    // ---- load 32 elements/lane, coalesced (8 independent dwordx4) ----
    float4 v[8];
#pragma unroll
    for (int s = 0; s < 8; ++s)
        v[s] = *reinterpret_cast<const float4*>(xr + s * 256 + lane * 4);

    // ---- per-lane candidate predicate mask (32 independent compares) ----
    unsigned m = 0;
#pragma unroll
    for (int s = 0; s < 8; ++s) {
#pragma unroll
        for (int j = 0; j < 4; ++j)
            m |= (f4elem(v[s], j) > T_LO ? 1u : 0u) << (s * 4 + j);
    }
    unsigned mycnt = __popc(m);

    // ---- wave-wide exclusive scan of per-lane counts (6 shfl steps) ----
    unsigned inc = mycnt;
#pragma unroll
    for (int d = 1; d < 64; d <<= 1) {
        unsigned u = __shfl_up(inc, d, 64);
        if (lane >= d) inc += u;
    }
    const unsigned base = inc - mycnt;
    const unsigned C = __shfl(inc, 63, 64);   // total candidates this row

    // ---- predicated LDS compaction (order irrelevant; cols carried) ----
    {
        unsigned pos = base;
#pragma unroll
        for (int s = 0; s < 8; ++s) {
#pragma unroll
            for (int j = 0; j < 4; ++j) {
                if (((m >> (s * 4 + j)) & 1u) && pos < CAP) {
                    my[pos] = make_float2(f4elem(v[s], j),
                                          __uint_as_float((unsigned)(s * 256 + lane * 4 + j)));
                    ++pos;
                }
            }
        }
    }

    if (C >= K_SEL && C <= CAP) {
        // ---- primary: early-exit bitwise radix select over 2 slots/lane ----
        float2 cd0 = my[lane];
        float2 cd1 = my[64 + lane];
        const bool ok0 = (unsigned)lane < C;
        const bool ok1 = (unsigned)(64 + lane) < C;
        const float    cv0 = ok0 ? cd0.x : 0.0f;
        const float    cv1 = ok1 ? cd1.x : 0.0f;
        const unsigned kb0 = __float_as_uint(cv0);  // >1.74 => positive => raw-bit order
        const unsigned kb1 = __float_as_uint(cv1);
        const unsigned cc0 = __float_as_uint(cd0.y);
        const unsigned cc1 = __float_as_uint(cd1.y);

        ull a0 = (C >= 64) ? ~0ull : ((1ull << C) - 1ull);
        ull a1 = (C <= 64) ? 0ull : ((C >= 128) ? ~0ull : ((1ull << (C - 64)) - 1ull));
        ull s0 = 0, s1 = 0;
        unsigned kk = K_SEL, na = C;

        if (na == kk) { s0 = a0; s1 = a1; kk = 0; }
        for (int b = 30; b >= 0 && kk; --b) {
            unsigned bit = 1u << b;
            ull b0 = __ballot((kb0 & bit) != 0) & a0;
            ull b1 = __ballot((kb1 & bit) != 0) & a1;
            unsigned cv = (unsigned)__popcll(b0) + (unsigned)__popcll(b1);
            if (cv >= kk) { a0 = b0; a1 = b1; na = cv; }
            else          { s0 |= b0; s1 |= b1; kk -= cv; a0 &= ~b0; a1 &= ~b1; na -= cv; }
            if (na == kk) { s0 |= a0; s1 |= a1; kk = 0; }
        }
        if (kk) {
            // bits exhausted: alive are exactly-equal values; take kk smallest cols
            ull e0 = a0, e1 = a1;
            for (unsigned t = 0; t < kk; ++t) {
                unsigned mymin = 0xFFFFFFFFu;
                if ((e0 >> lane) & 1ull) mymin = min(mymin, cc0);
                if ((e1 >> lane) & 1ull) mymin = min(mymin, cc1);
#pragma unroll
                for (int off = 32; off >= 1; off >>= 1)
                    mymin = min(mymin, (unsigned)__shfl_xor((int)mymin, off, 64));
                bool h0 = ((e0 >> lane) & 1ull) && cc0 == mymin;
                bool h1 = ((e1 >> lane) & 1ull) && cc1 == mymin;
                ull hb0 = __ballot(h0) & e0;
                ull hb1 = __ballot(h1) & e1;
                if (hb0) { s0 |= hb0 & (~hb0 + 1); e0 &= ~(hb0 & (~hb0 + 1)); }
                else     { s1 |= hb1 & (~hb1 + 1); e1 &= ~(hb1 & (~hb1 + 1)); }
            }
        }

        // ---- emit 40 pairs + column counts (XCD-local histogram copy) ----
        unsigned n0 = (unsigned)__popcll(s0);
        if ((s0 >> lane) & 1ull) {
            unsigned pos = (unsigned)__popcll(s0 & lm_lt);
            reinterpret_cast<float2*>(hdr)[pos] = make_float2(cv0, __uint_as_float(cc0));
            atomicAdd(&mycnt_arr[cc0], 1u);
        }
        if ((s1 >> lane) & 1ull) {
            unsigned pos = n0 + (unsigned)__popcll(s1 & lm_lt);
            reinterpret_cast<float2*>(hdr)[pos] = make_float2(cv1, __uint_as_float(cc1));
            atomicAdd(&mycnt_arr[cc1], 1u);
        }
    } else {
        // ---- fully general fallback (statistically never for N(0,1) data):
        //      K exact wave-argmax rounds, reloading from global (L1/L2-hot)
        unsigned rm = 0;
        for (int t = 0; t < K_SEL; ++t) {
            ull best = 0;
#pragma unroll
            for (int s = 0; s < 8; ++s) {
                float4 q = *reinterpret_cast<const float4*>(xr + s * 256 + lane * 4);
#pragma unroll
                for (int j = 0; j < 4; ++j) {
                    int slot = s * 4 + j;
                    if (!((rm >> slot) & 1u)) {
                        ull key = fkey(f4elem(q, j), (unsigned)(s * 256 + lane * 4 + j));
                        best = best > key ? best : key;
                    }
                }
            }
#pragma unroll
            for (int off = 32; off >= 1; off >>= 1) {
                ull o = __shfl_xor(best, off, 64);
                best = best > o ? best : o;
            }
#pragma unroll
            for (int s = 0; s < 8; ++s) {
                float4 q = *reinterpret_cast<const float4*>(xr + s * 256 + lane * 4);
#pragma unroll
                for (int j = 0; j < 4; ++j) {
                    int slot = s * 4 + j;
                    unsigned col = (unsigned)(s * 256 + lane * 4 + j);
                    if (!((rm >> slot) & 1u) && fkey(f4elem(q, j), col) == best) {
                        rm |= 1u << slot;
                        reinterpret_cast<float2*>(hdr)[t] =
                            make_float2(f4elem(q, j), __uint_as_float(col));
                        atomicAdd(&mycnt_arr[col], 1u);
                    }
                }
            }
        }
    }
}

// Kernel 2: sum 16 histogram copies; boost[d] = exp(-(duty*0.99 + 0.01*cnt/B
// - target)). 16 blocks x 128 threads: readers spread over all XCDs so the
// cross-XCD dirty-line probes run in parallel, not funneled through one L2.
__global__ __launch_bounds__(128) void kwta_boost_kernel(
        const float* __restrict__ duty, const unsigned* __restrict__ cnt,
        float* __restrict__ boost) {
    int d = blockIdx.x * 128 + threadIdx.x;
    unsigned s = 0;
#pragma unroll
    for (int g = 0; g < G_COPIES; ++g) s += cnt[((size_t)g << 11) + d];
    float mean = (float)s * (1.0f / 32768.0f);
    float nd = duty[d] * (1.0f - ALPHA_F) + ALPHA_F * mean;
    boost[d] = expf(-(nd - TARGET_F));
}

// Kernel 3: block-per-row; read 40 pairs from row header, build row in LDS,
// write fully-coalesced float4s (overwrites header with the real output).
__global__ __launch_bounds__(256) void kwta_scatter_kernel(
        float* __restrict__ out, const float* __restrict__ boost) {
    __shared__ float buf[D_COLS];
    const int t = threadIdx.x;
    const size_t rb = (size_t)blockIdx.x * D_COLS;

    float2 pr = make_float2(0.0f, 0.0f);
    if (t < K_SEL) pr = reinterpret_cast<const float2*>(out + rb)[t];

    float4 z = make_float4(0.0f, 0.0f, 0.0f, 0.0f);
    reinterpret_cast<float4*>(buf)[t * 2]     = z;
    reinterpret_cast<float4*>(buf)[t * 2 + 1] = z;
    __syncthreads();

    if (t < K_SEL) {
        unsigned col = __float_as_uint(pr.y);
        buf[col] = pr.x * boost[col];
    }
    __syncthreads();

    reinterpret_cast<float4*>(out + rb)[t * 2]     = reinterpret_cast<const float4*>(buf)[t * 2];
    reinterpret_cast<float4*>(out + rb)[t * 2 + 1] = reinterpret_cast<const float4*>(buf)[t * 2 + 1];
}

extern "C" void kernel_launch(void* const* d_in, const int* in_sizes, int n_in,
                              void* d_out, int out_size, void* d_ws, size_t ws_size,
                              hipStream_t stream) {
    const float* x    = (const float*)d_in[0];
    const float* duty = (const float*)d_in[1];
    float* out = (float*)d_out;

    unsigned* cnt   = (unsigned*)d_ws;                                 // 16 * 8 KB
    float*    boost = (float*)((char*)d_ws + (size_t)G_COPIES * 8192); // 8 KB

    // zero 16*8KB = 128KB of histograms: 32 blocks x 256 threads x 16B
    kwta_zero_kernel<<<G_COPIES * 8192 / 4096, 256, 0, stream>>>((uint4*)d_ws);

    kwta_topk_kernel<<<B_ROWS / 4, 256, 0, stream>>>(x, out, cnt);
    kwta_boost_kernel<<<D_COLS / 128, 128, 0, stream>>>(duty, cnt, boost);
    kwta_scatter_kernel<<<B_ROWS, 256, 0, stream>>>(out, boost);
}

// Round 6
// 173.828 us; speedup vs baseline: 1.6307x; 1.0159x over previous
//
#include <hip/hip_runtime.h>
#include <hip/hip_bf16.h>

typedef unsigned long long ull;

#define B_ROWS 32768
#define D_COLS 2048
#define K_SEL  40
#define T_LO   1.74f          // P(x>1.74)=0.0409 -> C ~ 84 +- 9, in [40,128] at ~4.9 sigma
#define CAP    128            // 2 slots per lane
#define ALPHA_F  0.01f
#define TARGET_F 0.01953125f  // 40/2048 exact
#define G_COPIES 16           // histogram copies; multiple of 8 => XCD-local atomics

__device__ __forceinline__ ull fkey(float vv, unsigned col) {
    // monotone (value desc via max, index asc via ~col) 64-bit key
    unsigned bits = __float_as_uint(vv);
    unsigned sk = (bits & 0x80000000u) ? ~bits : (bits | 0x80000000u);
    return ((ull)sk << 32) | (ull)(unsigned)(~col);
}

__device__ __forceinline__ float f4elem(const float4& q, int j) {
    return j == 0 ? q.x : j == 1 ? q.y : j == 2 ? q.z : q.w;
}

// Kernel 0: zero the privatized histograms (rocclr fillBuffer launches a tiny
// grid for small buffers; ~18us serialized for 1MB. DIY at full BW.)
__global__ __launch_bounds__(256) void kwta_zero_kernel(uint4* __restrict__ p) {
    p[blockIdx.x * 256 + threadIdx.x] = make_uint4(0u, 0u, 0u, 0u);
}

// Kernel 1: per-row exact top-K, one wave per row. Emits 40 (val,col) pairs
// into the first 320B of the row's out-slice (scratch; kernel 3 overwrites
// the row) + per-column selection counts into a PRIVATIZED histogram copy.
// NOTE: __launch_bounds__(256,3) -> <=85 VGPR. (256,8) forced VGPR=32 and
// spilled the 8xfloat4 row cache to scratch (R2: WRITE_SIZE 245MB = spills).
__global__ __launch_bounds__(256, 3) void kwta_topk_kernel(
        const float* __restrict__ x, float* __restrict__ out,
        unsigned* __restrict__ cnt) {
    __shared__ float2 cands[4][CAP];

    const int lane = threadIdx.x & 63;
    const int wid  = threadIdx.x >> 6;
    const int row  = blockIdx.x * 4 + wid;
    const float* xr = x + (size_t)row * D_COLS;
    const ull lm_lt = (1ull << lane) - 1ull;
    float2* my = cands[wid];
    float* hdr = out + (size_t)row * D_COLS;
    unsigned* mycnt_arr = cnt + ((size_t)(blockIdx.x & (G_COPIES - 1)) << 11);

    // ---- load 32 elements/lane, coalesced (8 independent dwordx4) ----
    float4 v[8];
#pragma unroll
    for (int s = 0; s < 8; ++s)
        v[s] = *reinterpret_cast<const float4*>(xr + s * 256 + lane * 4);

    // ---- per-lane candidate predicate mask (32 independent compares) ----
    unsigned m = 0;
#pragma unroll
    for (int s = 0; s < 8; ++s) {
#pragma unroll
        for (int j = 0; j < 4; ++j)
            m |= (f4elem(v[s], j) > T_LO ? 1u : 0u) << (s * 4 + j);
    }
    unsigned mycnt = __popc(m);

    // ---- wave-wide exclusive scan of per-lane counts (6 shfl steps) ----
    unsigned inc = mycnt;
#pragma unroll
    for (int d = 1; d < 64; d <<= 1) {
        unsigned u = __shfl_up(inc, d, 64);
        if (lane >= d) inc += u;
    }
    const unsigned base = inc - mycnt;
    const unsigned C = __shfl(inc, 63, 64);   // total candidates this row

    // ---- predicated LDS compaction (order irrelevant; cols carried) ----
    {
        unsigned pos = base;
#pragma unroll
        for (int s = 0; s < 8; ++s) {
#pragma unroll
            for (int j = 0; j < 4; ++j) {
                if (((m >> (s * 4 + j)) & 1u) && pos < CAP) {
                    my[pos] = make_float2(f4elem(v[s], j),
                                          __uint_as_float((unsigned)(s * 256 + lane * 4 + j)));
                    ++pos;
                }
            }
        }
    }

    if (C >= K_SEL && C <= CAP) {
        // ---- primary: early-exit bitwise radix select over 2 slots/lane ----
        float2 cd0 = my[lane];
        float2 cd1 = my[64 + lane];
        const bool ok0 = (unsigned)lane < C;
        const bool ok1 = (unsigned)(64 + lane) < C;
        const float    cv0 = ok0 ? cd0.x : 0.0f;
        const float    cv1 = ok1 ? cd1.x : 0.0f;
        const unsigned kb0 = __float_as_uint(cv0);  // >1.74 => positive => raw-bit order
        const unsigned kb1 = __float_as_uint(cv1);
        const unsigned cc0 = __float_as_uint(cd0.y);
        const unsigned cc1 = __float_as_uint(cd1.y);

        ull a0 = (C >= 64) ? ~0ull : ((1ull << C) - 1ull);
        ull a1 = (C <= 64) ? 0ull : ((C >= 128) ? ~0ull : ((1ull << (C - 64)) - 1ull));
        ull s0 = 0, s1 = 0;
        unsigned kk = K_SEL, na = C;

        if (na == kk) { s0 = a0; s1 = a1; kk = 0; }
        for (int b = 30; b >= 0 && kk; --b) {
            unsigned bit = 1u << b;
            ull b0 = __ballot((kb0 & bit) != 0) & a0;
            ull b1 = __ballot((kb1 & bit) != 0) & a1;
            unsigned cv = (unsigned)__popcll(b0) + (unsigned)__popcll(b1);
            if (cv >= kk) { a0 = b0; a1 = b1; na = cv; }
            else          { s0 |= b0; s1 |= b1; kk -= cv; a0 &= ~b0; a1 &= ~b1; na -= cv; }
            if (na == kk) { s0 |= a0; s1 |= a1; kk = 0; }
        }
        if (kk) {
            // bits exhausted: alive are exactly-equal values; take kk smallest cols
            ull e0 = a0, e1 = a1;
            for (unsigned t = 0; t < kk; ++t) {
                unsigned mymin = 0xFFFFFFFFu;
                if ((e0 >> lane) & 1ull) mymin = min(mymin, cc0);
                if ((e1 >> lane) & 1ull) mymin = min(mymin, cc1);
#pragma unroll
                for (int off = 32; off >= 1; off >>= 1)
                    mymin = min(mymin, (unsigned)__shfl_xor((int)mymin, off, 64));
                bool h0 = ((e0 >> lane) & 1ull) && cc0 == mymin;
                bool h1 = ((e1 >> lane) & 1ull) && cc1 == mymin;
                ull hb0 = __ballot(h0) & e0;
                ull hb1 = __ballot(h1) & e1;
                if (hb0) { s0 |= hb0 & (~hb0 + 1); e0 &= ~(hb0 & (~hb0 + 1)); }
                else     { s1 |= hb1 & (~hb1 + 1); e1 &= ~(hb1 & (~hb1 + 1)); }
            }
        }

        // ---- emit 40 pairs + column counts (XCD-local histogram copy) ----
        unsigned n0 = (unsigned)__popcll(s0);
        if ((s0 >> lane) & 1ull) {
            unsigned pos = (unsigned)__popcll(s0 & lm_lt);
            reinterpret_cast<float2*>(hdr)[pos] = make_float2(cv0, __uint_as_float(cc0));
            atomicAdd(&mycnt_arr[cc0], 1u);
        }
        if ((s1 >> lane) & 1ull) {
            unsigned pos = n0 + (unsigned)__popcll(s1 & lm_lt);
            reinterpret_cast<float2*>(hdr)[pos] = make_float2(cv1, __uint_as_float(cc1));
            atomicAdd(&mycnt_arr[cc1], 1u);
        }
    } else {
        // ---- fully general fallback (statistically never for N(0,1) data):
        //      K exact wave-argmax rounds, reloading from global (L1/L2-hot)
        unsigned rm = 0;
        for (int t = 0; t < K_SEL; ++t) {
            ull best = 0;
#pragma unroll
            for (int s = 0; s < 8; ++s) {
                float4 q = *reinterpret_cast<const float4*>(xr + s * 256 + lane * 4);
#pragma unroll
                for (int j = 0; j < 4; ++j) {
                    int slot = s * 4 + j;
                    if (!((rm >> slot) & 1u)) {
                        ull key = fkey(f4elem(q, j), (unsigned)(s * 256 + lane * 4 + j));
                        best = best > key ? best : key;
                    }
                }
            }
#pragma unroll
            for (int off = 32; off >= 1; off >>= 1) {
                ull o = __shfl_xor(best, off, 64);
                best = best > o ? best : o;
            }
#pragma unroll
            for (int s = 0; s < 8; ++s) {
                float4 q = *reinterpret_cast<const float4*>(xr + s * 256 + lane * 4);
#pragma unroll
                for (int j = 0; j < 4; ++j) {
                    int slot = s * 4 + j;
                    unsigned col = (unsigned)(s * 256 + lane * 4 + j);
                    if (!((rm >> slot) & 1u) && fkey(f4elem(q, j), col) == best) {
                        rm |= 1u << slot;
                        reinterpret_cast<float2*>(hdr)[t] =
                            make_float2(f4elem(q, j), __uint_as_float(col));
                        atomicAdd(&mycnt_arr[col], 1u);
                    }
                }
            }
        }
    }
}

// Kernel 2: sum 16 histogram copies; boost[d] = exp(-(duty*0.99 + 0.01*cnt/B
// - target)). 16 blocks x 128 threads: readers spread over all XCDs.
__global__ __launch_bounds__(128) void kwta_boost_kernel(
        const float* __restrict__ duty, const unsigned* __restrict__ cnt,
        float* __restrict__ boost) {
    int d = blockIdx.x * 128 + threadIdx.x;
    unsigned s = 0;
#pragma unroll
    for (int g = 0; g < G_COPIES; ++g) s += cnt[((size_t)g << 11) + d];
    float mean = (float)s * (1.0f / 32768.0f);
    float nd = duty[d] * (1.0f - ALPHA_F) + ALPHA_F * mean;
    boost[d] = expf(-(nd - TARGET_F));
}

// Kernel 3: block-per-row; read 40 pairs from row header, build row in LDS,
// write fully-coalesced float4s (overwrites header with the real output).
__global__ __launch_bounds__(256) void kwta_scatter_kernel(
        float* __restrict__ out, const float* __restrict__ boost) {
    __shared__ float buf[D_COLS];
    const int t = threadIdx.x;
    const size_t rb = (size_t)blockIdx.x * D_COLS;

    float2 pr = make_float2(0.0f, 0.0f);
    if (t < K_SEL) pr = reinterpret_cast<const float2*>(out + rb)[t];

    float4 z = make_float4(0.0f, 0.0f, 0.0f, 0.0f);
    reinterpret_cast<float4*>(buf)[t * 2]     = z;
    reinterpret_cast<float4*>(buf)[t * 2 + 1] = z;
    __syncthreads();

    if (t < K_SEL) {
        unsigned col = __float_as_uint(pr.y);
        buf[col] = pr.x * boost[col];
    }
    __syncthreads();

    reinterpret_cast<float4*>(out + rb)[t * 2]     = reinterpret_cast<const float4*>(buf)[t * 2];
    reinterpret_cast<float4*>(out + rb)[t * 2 + 1] = reinterpret_cast<const float4*>(buf)[t * 2 + 1];
}

extern "C" void kernel_launch(void* const* d_in, const int* in_sizes, int n_in,
                              void* d_out, int out_size, void* d_ws, size_t ws_size,
                              hipStream_t stream) {
    const float* x    = (const float*)d_in[0];
    const float* duty = (const float*)d_in[1];
    float* out = (float*)d_out;

    unsigned* cnt   = (unsigned*)d_ws;                                 // 16 * 8 KB
    float*    boost = (float*)((char*)d_ws + (size_t)G_COPIES * 8192); // 8 KB

    // zero 16*8KB = 128KB of histograms: 32 blocks x 256 threads x 16B
    kwta_zero_kernel<<<G_COPIES * 8192 / 4096, 256, 0, stream>>>((uint4*)d_ws);

    kwta_topk_kernel<<<B_ROWS / 4, 256, 0, stream>>>(x, out, cnt);
    kwta_boost_kernel<<<D_COLS / 128, 128, 0, stream>>>(duty, cnt, boost);
    kwta_scatter_kernel<<<B_ROWS, 256, 0, stream>>>(out, boost);
}